// Round 3
// baseline (116.795 us; speedup 1.0000x reference)
//
#include <hip/hip_runtime.h>
#include <hip/hip_cooperative_groups.h>
#include <math.h>

namespace cg = cooperative_groups;

#define TWO_PI_F 6.28318530717958647692f
#define BN_EPS_F 1e-5f

// cooperative path config: 1024 blocks * 256 thr = 4 blocks/CU on 256 CUs
#define NBLK 1024
#define NT 256

// fallback (proven 3-kernel) config
#define NB1 2048
#define NB2 1024

// ---------------------------------------------------------------------------
// Workspace float offsets.
// Cooperative path (all cross-block data via device-scope atomics or a
// kernel boundary -- NO plain-store/plain-load across grid.sync):
//   [MKEY_OFF..+2)  : uint min/max keys (atomicMin/atomicMax, init by k0)
//   [STAT_OFF..+8)  : BN stat accumulators (atomicAdd, zeroed by k0)
//   [CTAB_OFF..+576): UrT[16][16] | UiT[16][16] | AT[16][4]  (k0 -> fused,
//                     coherent via kernel boundary, read-only in fused)
// Fallback path keeps the proven layout (the two paths are mutually
// exclusive after the host-side gate / launch-error detection).
// ---------------------------------------------------------------------------
#define MKEY_OFF 0
#define STAT_OFF 4
#define CTAB_OFF 16
#define BMIN_OFF 256
#define BMAX_OFF 2304
#define TAB_OFF 4352
#define SSLOT_OFF 4992

// monotonic float<->uint order mapping (no NaNs in randn inputs)
__device__ __forceinline__ unsigned fkey(float f) {
  unsigned u = __float_as_uint(f);
  return u ^ (unsigned(int(u) >> 31) | 0x80000000u);
}
__device__ __forceinline__ float funkey(unsigned k) {
  unsigned u = (k & 0x80000000u) ? (k ^ 0x80000000u) : ~k;
  return __uint_as_float(u);
}

// Column `col` of the fixed 3-layer RY/RZ/CNOT unitary (proven numerics).
__device__ __forceinline__ void build_ucol(int col, const float* __restrict__ w,
                                           float* sr, float* si) {
#pragma unroll
  for (int k = 0; k < 16; ++k) { sr[k] = (k == col) ? 1.f : 0.f; si[k] = 0.f; }
#pragma unroll
  for (int l = 0; l < 3; ++l) {
#pragma unroll
    for (int i = 0; i < 4; ++i) {
      const int m = 8 >> i;
      float ryc, rys, rzc, rzs;
      __sincosf(0.5f * w[(l * 4 + i) * 2 + 0], &rys, &ryc);
      __sincosf(0.5f * w[(l * 4 + i) * 2 + 1], &rzs, &rzc);
#pragma unroll
      for (int k = 0; k < 16; ++k) {
        if (!(k & m)) {
          int k1 = k | m;
          float a0r = sr[k], a0i = si[k], a1r = sr[k1], a1i = si[k1];
          sr[k] = ryc * a0r - rys * a1r;
          si[k] = ryc * a0i - rys * a1i;
          sr[k1] = rys * a0r + ryc * a1r;
          si[k1] = rys * a0i + ryc * a1i;
        }
      }
#pragma unroll
      for (int k = 0; k < 16; ++k) {
        float ps = (k & m) ? rzs : -rzs;
        float rr = sr[k], ii = si[k];
        sr[k] = rr * rzc - ii * ps;
        si[k] = rr * ps + ii * rzc;
      }
    }
#pragma unroll
    for (int c = 0; c < 4; ++c) {
      const int mc = 8 >> c;
      const int mt = 8 >> ((c + 1) & 3);
#pragma unroll
      for (int k = 0; k < 16; ++k) {
        if ((k & mc) && !(k & mt)) {
          int k2 = k | mt;
          float tt;
          tt = sr[k]; sr[k] = sr[k2]; sr[k2] = tt;
          tt = si[k]; si[k] = si[k2]; si[k2] = tt;
        }
      }
    }
  }
}

// ===========================================================================
// K0: one block. Build tables into CTAB (kernel boundary makes them coherent
// for the cooperative kernel's read-only loads), init atomic accumulators.
// ===========================================================================
__global__ __launch_bounds__(128) void k0_init(const float* __restrict__ w,
                                               const float* __restrict__ fc_w,
                                               float* __restrict__ wsf) {
  int tid = threadIdx.x;
  if (tid < 16) {
    float sr[16], si[16];
    build_ucol(tid, w, sr, si);
#pragma unroll
    for (int k = 0; k < 16; ++k) {
      wsf[CTAB_OFF + tid * 16 + k] = sr[k];
      wsf[CTAB_OFF + 256 + tid * 16 + k] = si[k];
    }
  } else if (tid < 24) {
    wsf[STAT_OFF + (tid - 16)] = 0.f;  // BN stat accumulators (re-poisoned
                                       // every launch: graph-replay safe)
  } else if (tid == 24) {
    unsigned* mk = (unsigned*)wsf + MKEY_OFF;
    mk[0] = 0xFFFFFFFFu;  // min-key sentinel
    mk[1] = 0u;           // max-key sentinel
  } else if (tid >= 64 && tid < 128) {
    // AT[k][j] = sum_i fc_w[j][i] * Zparity(k,i)
    int e = tid - 64, k = e >> 2, j = e & 3;
    float s = 0.f;
#pragma unroll
    for (int i = 0; i < 4; ++i)
      s += fc_w[j * 4 + i] * ((k & (8 >> i)) ? -1.f : 1.f);
    wsf[CTAB_OFF + 512 + k * 4 + j] = s;
  }
}

// Single-sample fused circuit+linear: o = A|U v|^2 (bias cancels in BN).
// tab is wave-uniform const restrict -> scalar (s_load) table reads.
__device__ __forceinline__ void qfc_one(const float* __restrict__ tab,
                                        const float* c, const float* s,
                                        float* o) {
  const float* __restrict__ Ur = tab;
  const float* __restrict__ Ui = tab + 256;
  const float* __restrict__ At = tab + 512;
  float A01[4] = {c[0] * c[1], c[0] * s[1], s[0] * c[1], s[0] * s[1]};
  float A23[4] = {c[2] * c[3], c[2] * s[3], s[2] * c[3], s[2] * s[3]};
  float yr[16], yi[16];
#pragma unroll
  for (int k = 0; k < 16; ++k) { yr[k] = yi[k] = 0.f; }
#pragma unroll
  for (int a = 0; a < 16; ++a) {
    float va = A01[a >> 2] * A23[a & 3];
#pragma unroll
    for (int k = 0; k < 16; ++k) {
      yr[k] = fmaf(Ur[a * 16 + k], va, yr[k]);
      yi[k] = fmaf(Ui[a * 16 + k], va, yi[k]);
    }
  }
#pragma unroll
  for (int j = 0; j < 4; ++j) o[j] = 0.f;
#pragma unroll
  for (int k = 0; k < 16; ++k) {
    float p = fmaf(yr[k], yr[k], yi[k] * yi[k]);
#pragma unroll
    for (int j = 0; j < 4; ++j) o[j] = fmaf(At[k * 4 + j], p, o[j]);
  }
}

// ===========================================================================
// Cooperative kernel: x read once (rows live in registers across barriers),
// out written once post-BN. All cross-block traffic is device-scope atomics.
// ===========================================================================
__global__ __launch_bounds__(NT, 4) void fused(
    const float* __restrict__ x, unsigned* __restrict__ mk,
    float* __restrict__ stp, const float* __restrict__ tab,
    const float* __restrict__ gamma, const float* __restrict__ beta,
    float* __restrict__ out, int B) {
  const int tid = threadIdx.x;
  const int gtid = blockIdx.x * NT + tid;
  const int H = NBLK * NT;  // 262144
  const int wv = tid >> 6, ln = tid & 63;
  __shared__ float smn[4], smx[4];
  __shared__ float red[4][8];
  __shared__ float sbc[2];
  __shared__ float sst[8];

  // ---- Phase 1: load rows (keep in regs), block min/max -> 2 atomics
  const int s0 = gtid, s1 = gtid + H;
  const bool h0 = s0 < B, h1 = s1 < B;
  float4 xa = h0 ? *(const float4*)(x + (size_t)s0 * 16) : make_float4(0, 0, 0, 0);
  float4 xb = h1 ? *(const float4*)(x + (size_t)s1 * 16) : make_float4(0, 0, 0, 0);

  float fmn = __builtin_inff(), fmx = -__builtin_inff();
  if (h0) {
    fmn = fminf(fminf(xa.x, xa.y), fminf(xa.z, xa.w));
    fmx = fmaxf(fmaxf(xa.x, xa.y), fmaxf(xa.z, xa.w));
  }
  if (h1) {
    fmn = fminf(fmn, fminf(fminf(xb.x, xb.y), fminf(xb.z, xb.w)));
    fmx = fmaxf(fmx, fmaxf(fmaxf(xb.x, xb.y), fmaxf(xb.z, xb.w)));
  }
#pragma unroll
  for (int d = 32; d; d >>= 1) {
    fmn = fminf(fmn, __shfl_down(fmn, d));
    fmx = fmaxf(fmx, __shfl_down(fmx, d));
  }
  if (ln == 0) { smn[wv] = fmn; smx[wv] = fmx; }
  __syncthreads();
  if (tid == 0) {
    float bm = fminf(fminf(smn[0], smn[1]), fminf(smn[2], smn[3]));
    float bM = fmaxf(fmaxf(smx[0], smx[1]), fmaxf(smx[2], smx[3]));
    atomicMin(mk + 0, fkey(bm));
    atomicMax(mk + 1, fkey(bM));
  }

  cg::this_grid().sync();

  // ---- Phase 2: coherent min/max read; circuit+linear; BN partial atomics
  if (tid == 0) {
    unsigned kmin = __hip_atomic_load(mk + 0, __ATOMIC_RELAXED,
                                      __HIP_MEMORY_SCOPE_AGENT);
    unsigned kmax = __hip_atomic_load(mk + 1, __ATOMIC_RELAXED,
                                      __HIP_MEMORY_SCOPE_AGENT);
    sbc[0] = funkey(kmin);
    sbc[1] = funkey(kmax);
  }
  __syncthreads();
  const float gm = sbc[0], gM = sbc[1];
  const float ssc = TWO_PI_F * 0.5f / (gM - gm + 1e-8f);  // half-angle scale

  float a0[4] = {xa.x, xa.y, xa.z, xa.w};
  float a1[4] = {xb.x, xb.y, xb.z, xb.w};
  float c0[4], sn0[4], c1[4], sn1[4];
#pragma unroll
  for (int i = 0; i < 4; ++i) {
    __sincosf((a0[i] - gm) * ssc, &sn0[i], &c0[i]);
    __sincosf((a1[i] - gm) * ssc, &sn1[i], &c1[i]);
  }
  float o0[4], o1[4];
  qfc_one(tab, c0, sn0, o0);  // sequential pairs keep peak VGPRs < 128 cap
  qfc_one(tab, c1, sn1, o1);

  float vals[8];
#pragma unroll
  for (int j = 0; j < 4; ++j) {
    float v0 = h0 ? o0[j] : 0.f, v1 = h1 ? o1[j] : 0.f;
    vals[j] = v0 + v1;
    vals[4 + j] = fmaf(v0, v0, v1 * v1);
  }
#pragma unroll
  for (int j = 0; j < 8; ++j) {
#pragma unroll
    for (int d = 32; d; d >>= 1) vals[j] += __shfl_down(vals[j], d);
  }
  if (ln == 0) {
#pragma unroll
    for (int j = 0; j < 8; ++j) red[wv][j] = vals[j];
  }
  __syncthreads();
  if (tid < 8)
    atomicAdd(stp + tid, red[0][tid] + red[1][tid] + red[2][tid] + red[3][tid]);

  cg::this_grid().sync();

  // ---- Phase 3: coherent stat read, BN finalize on register-held o, write out
  if (tid < 8)
    sst[tid] = __hip_atomic_load(stp + tid, __ATOMIC_RELAXED,
                                 __HIP_MEMORY_SCOPE_AGENT);
  __syncthreads();

  const float inv = 1.0f / (float)B;
  float sc[4], sh[4];
#pragma unroll
  for (int j = 0; j < 4; ++j) {
    float mean = sst[j] * inv;
    float var = sst[4 + j] * inv - mean * mean;
    float is = rsqrtf(var + BN_EPS_F);
    sc[j] = gamma[j] * is;
    sh[j] = beta[j] - mean * sc[j];
  }
  if (h0)
    *(float4*)(out + (size_t)s0 * 4) =
        make_float4(fmaf(o0[0], sc[0], sh[0]), fmaf(o0[1], sc[1], sh[1]),
                    fmaf(o0[2], sc[2], sh[2]), fmaf(o0[3], sc[3], sh[3]));
  if (h1)
    *(float4*)(out + (size_t)s1 * 4) =
        make_float4(fmaf(o1[0], sc[0], sh[0]), fmaf(o1[1], sc[1], sh[1]),
                    fmaf(o1[2], sc[2], sh[2]), fmaf(o1[3], sc[3], sh[3]));
}

// ===========================================================================
// Fallback: the proven 111.3 µs 3-kernel pipeline (runs only if the
// cooperative path is gated off or its launch is rejected).
// ===========================================================================
__global__ __launch_bounds__(NT) void k1_scan_tab(const float* __restrict__ x,
                                                  const float* __restrict__ w,
                                                  const float* __restrict__ fc_w,
                                                  float* __restrict__ wsf, int B) {
  int r = blockIdx.x * NT + threadIdx.x;
  float fmn = __builtin_inff(), fmx = -__builtin_inff();
  if (r < B) {
    float4 v = *(const float4*)(x + (size_t)r * 16);
    fmn = fminf(fminf(v.x, v.y), fminf(v.z, v.w));
    fmx = fmaxf(fmaxf(v.x, v.y), fmaxf(v.z, v.w));
  }
#pragma unroll
  for (int d = 32; d; d >>= 1) {
    fmn = fminf(fmn, __shfl_down(fmn, d));
    fmx = fmaxf(fmx, __shfl_down(fmx, d));
  }
  __shared__ float smn[4], smx[4];
  int wv = threadIdx.x >> 6, ln = threadIdx.x & 63;
  if (ln == 0) { smn[wv] = fmn; smx[wv] = fmx; }
  __syncthreads();
  if (threadIdx.x == 0) {
    wsf[BMIN_OFF + blockIdx.x] =
        fminf(fminf(smn[0], smn[1]), fminf(smn[2], smn[3]));
    wsf[BMAX_OFF + blockIdx.x] =
        fmaxf(fmaxf(smx[0], smx[1]), fmaxf(smx[2], smx[3]));
  }
  if (blockIdx.x == 0) {
    int tid = threadIdx.x;
    if (tid < 16) {
      float sr[16], si[16];
      build_ucol(tid, w, sr, si);
#pragma unroll
      for (int k = 0; k < 16; ++k) {
        wsf[TAB_OFF + tid * 16 + k] = sr[k];
        wsf[TAB_OFF + 256 + tid * 16 + k] = si[k];
      }
    } else if (tid == 16) {
      for (int k = 0; k < 16; ++k)
        for (int j = 0; j < 4; ++j) {
          float s = 0.f;
          for (int i = 0; i < 4; ++i)
            s += fc_w[j * 4 + i] * ((k & (8 >> i)) ? -1.f : 1.f);
          wsf[TAB_OFF + 512 + k * 4 + j] = s;
        }
    }
  }
}

__device__ __forceinline__ void qfc_pair(const float* __restrict__ tab,
                                         const float* c0, const float* s0,
                                         const float* c1, const float* s1,
                                         float* o0, float* o1) {
  const float* __restrict__ Ur = tab;
  const float* __restrict__ Ui = tab + 256;
  const float* __restrict__ At = tab + 512;
  float A01_0[4] = {c0[0] * c0[1], c0[0] * s0[1], s0[0] * c0[1], s0[0] * s0[1]};
  float A23_0[4] = {c0[2] * c0[3], c0[2] * s0[3], s0[2] * c0[3], s0[2] * s0[3]};
  float A01_1[4] = {c1[0] * c1[1], c1[0] * s1[1], s1[0] * c1[1], s1[0] * s1[1]};
  float A23_1[4] = {c1[2] * c1[3], c1[2] * s1[3], s1[2] * c1[3], s1[2] * s1[3]};
  float yr0[16], yi0[16], yr1[16], yi1[16];
#pragma unroll
  for (int k = 0; k < 16; ++k) { yr0[k] = yi0[k] = yr1[k] = yi1[k] = 0.f; }
#pragma unroll
  for (int a = 0; a < 16; ++a) {
    float va0 = A01_0[a >> 2] * A23_0[a & 3];
    float va1 = A01_1[a >> 2] * A23_1[a & 3];
#pragma unroll
    for (int k = 0; k < 16; ++k) {
      float ur = Ur[a * 16 + k], ui = Ui[a * 16 + k];
      yr0[k] = fmaf(ur, va0, yr0[k]);
      yi0[k] = fmaf(ui, va0, yi0[k]);
      yr1[k] = fmaf(ur, va1, yr1[k]);
      yi1[k] = fmaf(ui, va1, yi1[k]);
    }
  }
#pragma unroll
  for (int j = 0; j < 4; ++j) { o0[j] = 0.f; o1[j] = 0.f; }
#pragma unroll
  for (int k = 0; k < 16; ++k) {
    float p0 = fmaf(yr0[k], yr0[k], yi0[k] * yi0[k]);
    float p1 = fmaf(yr1[k], yr1[k], yi1[k] * yi1[k]);
#pragma unroll
    for (int j = 0; j < 4; ++j) {
      float av = At[k * 4 + j];
      o0[j] = fmaf(av, p0, o0[j]);
      o1[j] = fmaf(av, p1, o1[j]);
    }
  }
}

__global__ __launch_bounds__(NT) void k2_main(const float* __restrict__ x,
                                              const float* __restrict__ wsf,
                                              float* __restrict__ sslot,
                                              float* __restrict__ out, int B) {
  const int tid = threadIdx.x;
  const int gtid = blockIdx.x * NT + tid;
  const int H = NB2 * NT;
  const int wv = tid >> 6, ln = tid & 63;
  const float* __restrict__ tab = wsf + TAB_OFF;

  float gm = __builtin_inff(), gM = -__builtin_inff();
#pragma unroll
  for (int q = 0; q < NB1 / 64; ++q) {
    int i = ln + q * 64;
    gm = fminf(gm, wsf[BMIN_OFF + i]);
    gM = fmaxf(gM, wsf[BMAX_OFF + i]);
  }
#pragma unroll
  for (int d = 32; d; d >>= 1) {
    gm = fminf(gm, __shfl_down(gm, d));
    gM = fmaxf(gM, __shfl_down(gM, d));
  }
  gm = __shfl(gm, 0);
  gM = __shfl(gM, 0);
  const float ssc = TWO_PI_F * 0.5f / (gM - gm + 1e-8f);

  const int s0 = gtid, s1 = gtid + H;
  const bool h0 = s0 < B, h1 = s1 < B;
  float4 xa = h0 ? *(const float4*)(x + (size_t)s0 * 16) : make_float4(0, 0, 0, 0);
  float4 xb = h1 ? *(const float4*)(x + (size_t)s1 * 16) : make_float4(0, 0, 0, 0);

  float a0[4] = {xa.x, xa.y, xa.z, xa.w};
  float a1[4] = {xb.x, xb.y, xb.z, xb.w};
  float c0[4], sn0[4], c1[4], sn1[4];
#pragma unroll
  for (int i = 0; i < 4; ++i) {
    __sincosf((a0[i] - gm) * ssc, &sn0[i], &c0[i]);
    __sincosf((a1[i] - gm) * ssc, &sn1[i], &c1[i]);
  }
  float o0[4], o1[4];
  qfc_pair(tab, c0, sn0, c1, sn1, o0, o1);

  if (h0)
    *(float4*)(out + (size_t)s0 * 4) = make_float4(o0[0], o0[1], o0[2], o0[3]);
  if (h1)
    *(float4*)(out + (size_t)s1 * 4) = make_float4(o1[0], o1[1], o1[2], o1[3]);

  float vals[8];
#pragma unroll
  for (int j = 0; j < 4; ++j) {
    float v0 = h0 ? o0[j] : 0.f, v1 = h1 ? o1[j] : 0.f;
    vals[j] = v0 + v1;
    vals[4 + j] = fmaf(v0, v0, v1 * v1);
  }
#pragma unroll
  for (int j = 0; j < 8; ++j) {
#pragma unroll
    for (int d = 32; d; d >>= 1) vals[j] += __shfl_down(vals[j], d);
  }
  __shared__ float red[4][8];
  if (ln == 0) {
#pragma unroll
    for (int j = 0; j < 8; ++j) red[wv][j] = vals[j];
  }
  __syncthreads();
  if (tid < 8) {
    sslot[blockIdx.x * 8 + tid] =
        red[0][tid] + red[1][tid] + red[2][tid] + red[3][tid];
  }
}

__global__ __launch_bounds__(NT) void k3_final(float* __restrict__ out,
                                               const float* __restrict__ sslot,
                                               const float* __restrict__ gamma,
                                               const float* __restrict__ beta,
                                               int B) {
  const int tid = threadIdx.x;
  const int gtid = blockIdx.x * NT + tid;
  const int H = NB2 * NT;
  const int ln = tid & 63;

  float v = 0.f;
#pragma unroll
  for (int k = 0; k < (NB2 * 8) / 64; ++k) v += sslot[k * 64 + ln];
#pragma unroll
  for (int d = 32; d >= 8; d >>= 1) v += __shfl_down(v, d);
  float st[8];
#pragma unroll
  for (int j = 0; j < 8; ++j) st[j] = __shfl(v, j);

  const float inv = 1.0f / (float)B;
  float sc[4], sh[4];
#pragma unroll
  for (int j = 0; j < 4; ++j) {
    float mean = st[j] * inv;
    float var = st[4 + j] * inv - mean * mean;
    float is = rsqrtf(var + BN_EPS_F);
    sc[j] = gamma[j] * is;
    sh[j] = beta[j] - mean * sc[j];
  }
#pragma unroll
  for (int p = 0; p < 2; ++p) {
    int s = gtid + p * H;
    if (s < B) {
      float4 q = *(float4*)(out + (size_t)s * 4);
      *(float4*)(out + (size_t)s * 4) =
          make_float4(fmaf(q.x, sc[0], sh[0]), fmaf(q.y, sc[1], sh[1]),
                      fmaf(q.z, sc[2], sh[2]), fmaf(q.w, sc[3], sh[3]));
    }
  }
}

extern "C" void kernel_launch(void* const* d_in, const int* in_sizes, int n_in,
                              void* d_out, int out_size, void* d_ws, size_t ws_size,
                              hipStream_t stream) {
  const float* x = (const float*)d_in[0];
  const float* w = (const float*)d_in[1];
  const float* fc_w = (const float*)d_in[2];
  const float* gamma = (const float*)d_in[4];
  const float* beta = (const float*)d_in[5];
  float* out = (float*)d_out;
  float* wsf = (float*)d_ws;
  int B = in_sizes[0] / 16;

  k0_init<<<1, 128, 0, stream>>>(w, fc_w, wsf);

  // Host-side, capture-safe gate: only attempt the cooperative launch if the
  // runtime certifies support AND full-grid co-residency (avoids a failed
  // stream-op poisoning graph capture). Cached across calls.
  static int coop_state = -1;  // -1 unknown, 0 no, 1 yes
  if (coop_state < 0) {
    int dev = 0;
    (void)hipGetDevice(&dev);
    int coop = 0;
    (void)hipDeviceGetAttribute(&coop, hipDeviceAttributeCooperativeLaunch, dev);
    int ncu = 0;
    (void)hipDeviceGetAttribute(&ncu, hipDeviceAttributeMultiprocessorCount, dev);
    int per_cu = 0;
    (void)hipOccupancyMaxActiveBlocksPerMultiprocessor(&per_cu,
                                                       (const void*)fused, NT, 0);
    coop_state = (coop && ncu > 0 && per_cu > 0 &&
                  (long long)per_cu * ncu >= NBLK)
                     ? 1
                     : 0;
  }

  hipError_t e = hipErrorUnknown;
  if (coop_state == 1 && B <= 2 * NBLK * NT) {
    unsigned* mk = (unsigned*)wsf + MKEY_OFF;
    float* stp = wsf + STAT_OFF;
    const float* tab = wsf + CTAB_OFF;
    void* args[] = {(void*)&x,     (void*)&mk,   (void*)&stp, (void*)&tab,
                    (void*)&gamma, (void*)&beta, (void*)&out, (void*)&B};
    e = hipLaunchCooperativeKernel((const void*)fused, dim3(NBLK), dim3(NT),
                                   args, 0, stream);
    if (e != hipSuccess) {
      (void)hipGetLastError();  // clear sticky error before fallback
      coop_state = 0;           // don't retry the coop path on later launches
    }
  }
  if (e != hipSuccess) {
    k1_scan_tab<<<NB1, NT, 0, stream>>>(x, w, fc_w, wsf, B);
    k2_main<<<NB2, NT, 0, stream>>>(x, wsf, wsf + SSLOT_OFF, out, B);
    k3_final<<<NB2, NT, 0, stream>>>(out, wsf + SSLOT_OFF, gamma, beta, B);
  }
}